// Round 6
// baseline (228.776 us; speedup 1.0000x reference)
//
#include <hip/hip_runtime.h>
#include <stdint.h>

#define AS1 __attribute__((address_space(1)))
#define AS3 __attribute__((address_space(3)))

typedef __bf16 bf16x8 __attribute__((ext_vector_type(8)));
typedef float f32x4 __attribute__((ext_vector_type(4)));

constexpr int NB = 8;     // batches
constexpr int N  = 2048;  // nodes
constexpr int F  = 128;   // features (in == out)

__device__ __forceinline__ unsigned short bf16r(float f) {
    unsigned u = __float_as_uint(f);
    return (unsigned short)((u + 0x7FFFu + ((u >> 16) & 1u)) >> 16);
}
__device__ __forceinline__ float bf2f(unsigned short s) {
    return __uint_as_float(((unsigned)s) << 16);
}

// ---------------------------------------------------------------------------
// Wb2 element layout (MFMA-B-operand native):
//   E(b, n, o) = b*N*F + (n>>3)*1024 + o*8 + (n&7)
// Lane needing B[k = kb+quad*8 .. +8][o] reads 16 contiguous bytes at
//   byte(b) + ((kb>>3)+quad)*2048 + o*16.
// ---------------------------------------------------------------------------

// K1 (fused with old K2): per 64-node block
//   Wh = h @ W^T (bf16 MFMA, fp32 acc);  e[n] = sum_o Wh[n][o]*a2[o]
//   p = exp(e);  p16[n] = bf16(p);  Wb2[n][o] = bf16(bf2f(p16)*Wh[n][o])
__global__ __launch_bounds__(256) void k1_wh(const float* __restrict__ h,
                                             const float* __restrict__ W,
                                             const float* __restrict__ a,
                                             unsigned short* __restrict__ Wb2,
                                             unsigned short* __restrict__ p16) {
    __shared__ float epart[2][64];

    const int tid  = threadIdx.x;
    const int lane = tid & 63, wid = tid >> 6;
    const int quad = lane >> 4, l15 = lane & 15;
    const int wm = wid >> 1, wn = wid & 1;
    const int m0 = blockIdx.x * 64;
    const int batch = m0 >> 11;
    const int nbase = m0 & 2047;

    f32x4 acc[2][4] = {};

#pragma unroll
    for (int kk = 0; kk < 4; ++kk) {
        const int k = kk * 32 + quad * 8;
        bf16x8 afr[2], bfr[4];
#pragma unroll
        for (int rt = 0; rt < 2; ++rt) {
            const float* src = h + (size_t)(m0 + wm * 32 + rt * 16 + l15) * F + k;
            float4 x0 = *(const float4*)src;
            float4 x1 = *(const float4*)(src + 4);
            afr[rt][0] = (__bf16)x0.x; afr[rt][1] = (__bf16)x0.y;
            afr[rt][2] = (__bf16)x0.z; afr[rt][3] = (__bf16)x0.w;
            afr[rt][4] = (__bf16)x1.x; afr[rt][5] = (__bf16)x1.y;
            afr[rt][6] = (__bf16)x1.z; afr[rt][7] = (__bf16)x1.w;
        }
#pragma unroll
        for (int ct = 0; ct < 4; ++ct) {
            const int o = wn * 64 + ct * 16 + l15;
            const float* src = W + (size_t)o * F + k;
            float4 x0 = *(const float4*)src;
            float4 x1 = *(const float4*)(src + 4);
            bfr[ct][0] = (__bf16)x0.x; bfr[ct][1] = (__bf16)x0.y;
            bfr[ct][2] = (__bf16)x0.z; bfr[ct][3] = (__bf16)x0.w;
            bfr[ct][4] = (__bf16)x1.x; bfr[ct][5] = (__bf16)x1.y;
            bfr[ct][6] = (__bf16)x1.z; bfr[ct][7] = (__bf16)x1.w;
        }
#pragma unroll
        for (int rt = 0; rt < 2; ++rt)
#pragma unroll
            for (int ct = 0; ct < 4; ++ct)
                acc[rt][ct] = __builtin_amdgcn_mfma_f32_16x16x32_bf16(
                    afr[rt], bfr[ct], acc[rt][ct], 0, 0, 0);
    }

    // e-partials: lane's share of sum_o Wh[row][o]*a2[o] over its 4 o-columns,
    // reduced across the 16 l15 lanes in-wave, across wn via LDS.
    float a2v[4];
#pragma unroll
    for (int ct = 0; ct < 4; ++ct) a2v[ct] = a[F + wn * 64 + ct * 16 + l15];

    float ep[2][4];
#pragma unroll
    for (int rt = 0; rt < 2; ++rt)
#pragma unroll
        for (int g = 0; g < 4; ++g) {
            float s = 0.f;
#pragma unroll
            for (int ct = 0; ct < 4; ++ct) s += acc[rt][ct][g] * a2v[ct];
            ep[rt][g] = s;
        }
#pragma unroll
    for (int m = 1; m < 16; m <<= 1)
#pragma unroll
        for (int rt = 0; rt < 2; ++rt)
#pragma unroll
            for (int g = 0; g < 4; ++g)
                ep[rt][g] += __shfl_xor(ep[rt][g], m);

    if (l15 == 0)
#pragma unroll
        for (int rt = 0; rt < 2; ++rt)
#pragma unroll
            for (int g = 0; g < 4; ++g)
                epart[wn][wm * 32 + rt * 16 + quad * 4 + g] = ep[rt][g];
    __syncthreads();

#pragma unroll
    for (int rt = 0; rt < 2; ++rt)
#pragma unroll
        for (int ct = 0; ct < 4; ++ct) {
            const int o  = wn * 64 + ct * 16 + l15;
            const int r0 = wm * 32 + rt * 16 + quad * 4;
            const int n0 = nbase + r0;
            ushort4 v;
#pragma unroll
            for (int g = 0; g < 4; ++g) {
                const float e  = epart[0][r0 + g] + epart[1][r0 + g];
                const float pf = bf2f(bf16r(expf(e)));   // rounded p, consistent w/ p16
                (&v.x)[g] = bf16r(pf * acc[rt][ct][g]);
            }
            size_t off = (size_t)batch * N * F + (size_t)(n0 >> 3) * 1024 + o * 8 + (n0 & 7);
            *(ushort4*)&Wb2[off] = v;
        }

    if (tid < 64) {
        const float e = epart[0][tid] + epart[1][tid];
        p16[batch * N + nbase + tid] = bf16r(expf(e));
    }
}

// K3: out[b][i][o] = (sum_j adj[b][i][j] * Wb2[j][o]) / (sum_j adj * p[j])
// Block tile 32(i) x 128(o); 4 waves (wm=row-half, wn=o-half), wave 16x64.
// dbuf global_load_lds staging of adj, BK=64 (8 KB/chunk, 2 instr/wave).
// 16B-chunk XOR swizzle (slot = gchunk ^ (row&15)) -> conflict-free b128 reads.
// XCD-aware mapping: batch = blockIdx.x & 7 pins each batch's Wb2 (512 KB)
// into one XCD's L2. Grid 512 = 2 blocks/CU.
__global__ __launch_bounds__(256) void k3_attn(const float* __restrict__ adj,
                                               const unsigned short* __restrict__ Wb2,
                                               const unsigned short* __restrict__ p16,
                                               float* __restrict__ out) {
    __shared__ __align__(16) float At[2][32 * 64];   // 8 KB per buffer

    const int tid  = threadIdx.x;
    const int lane = tid & 63, wid = tid >> 6;
    const int quad = lane >> 4, l15 = lane & 15;
    const int wm = wid >> 1, wn = wid & 1;
    const int b  = blockIdx.x & 7;
    const int i0 = (blockIdx.x >> 3) * 32;

    const float* adjb = adj + (size_t)b * N * N;
    const char*  bB   = (const char*)Wb2 + (size_t)b * N * F * 2 + wn * 1024 + l15 * 16;
    const unsigned short* pb = p16 + b * N;

    // Staging: instr ii = wid*2+s covers LDS bytes ii*1024 (rows ii*4..+3).
    // Lane: row ri = ii*4 + (lane>>4); LDS slot lane&15 must hold global
    // 16B-chunk (lane&15)^(ri&15).
    const int lrow = lane >> 4, lslot = lane & 15;
    auto stage = [&](int buf, int c) {
#pragma unroll
        for (int s = 0; s < 2; ++s) {
            const int ii = wid * 2 + s;
            const int ri = ii * 4 + lrow;
            const int gf = ((lslot ^ (ri & 15)) << 2);
            const float* g = adjb + (size_t)(i0 + ri) * N + c * 64 + gf;
            __builtin_amdgcn_global_load_lds((const AS1 void*)g,
                (AS3 void*)((char*)&At[buf][0] + ii * 1024), 16, 0, 0);
        }
    };

    f32x4 acc[4] = {};
    f32x4 dacc = {};

    stage(0, 0);

    for (int c = 0; c < 32; ++c) {
        const int cur = c & 1;
        __syncthreads();              // drains stage(c) + prev chunk's LDS reads
        if (c + 1 < 32) stage(cur ^ 1, c + 1);

#pragma unroll
        for (int ks = 0; ks < 2; ++ks) {
            // A frag: row wm*16+l15, global chunks g0=ks*8+quad*2, g0+1
            const char* rowb = (const char*)&At[cur][0] + (wm * 16 + l15) * 256;
            const int slot0 = (ks * 8 + quad * 2) ^ l15;
            f32x4 x0 = *(const f32x4*)(rowb + slot0 * 16);
            f32x4 x1 = *(const f32x4*)(rowb + (slot0 ^ 1) * 16);

            const char* bp = bB + ((size_t)c * 8 + ks * 4 + quad) * 2048;
            bf16x8 b0 = *(const bf16x8*)bp;
            bf16x8 b1 = *(const bf16x8*)(bp + 256);
            bf16x8 b2 = *(const bf16x8*)(bp + 512);
            bf16x8 b3 = *(const bf16x8*)(bp + 768);
            bf16x8 pv = *(const bf16x8*)(pb + c * 64 + ks * 32 + quad * 8);

            bf16x8 af;   // adj in {0,1}: cvt exact; p folded into B
            af[0] = (__bf16)x0[0]; af[1] = (__bf16)x0[1];
            af[2] = (__bf16)x0[2]; af[3] = (__bf16)x0[3];
            af[4] = (__bf16)x1[0]; af[5] = (__bf16)x1[1];
            af[6] = (__bf16)x1[2]; af[7] = (__bf16)x1[3];

            acc[0] = __builtin_amdgcn_mfma_f32_16x16x32_bf16(af, b0, acc[0], 0, 0, 0);
            acc[1] = __builtin_amdgcn_mfma_f32_16x16x32_bf16(af, b1, acc[1], 0, 0, 0);
            acc[2] = __builtin_amdgcn_mfma_f32_16x16x32_bf16(af, b2, acc[2], 0, 0, 0);
            acc[3] = __builtin_amdgcn_mfma_f32_16x16x32_bf16(af, b3, acc[3], 0, 0, 0);
            dacc   = __builtin_amdgcn_mfma_f32_16x16x32_bf16(af, pv, dacc, 0, 0, 0);
        }
    }

    // dacc reg g = denom for row quad*4+g — same row mapping as acc.
    float inv[4];
#pragma unroll
    for (int g = 0; g < 4; ++g) inv[g] = 1.0f / dacc[g];

    float* ob = out + (size_t)b * N * F;
#pragma unroll
    for (int ct = 0; ct < 4; ++ct) {
        const int o = wn * 64 + ct * 16 + l15;
#pragma unroll
        for (int g = 0; g < 4; ++g) {
            const int i = i0 + wm * 16 + quad * 4 + g;
            ob[(size_t)i * F + o] = acc[ct][g] * inv[g];
        }
    }
}

// ---------------------------------------------------------------------------
extern "C" void kernel_launch(void* const* d_in, const int* in_sizes, int n_in,
                              void* d_out, int out_size, void* d_ws, size_t ws_size,
                              hipStream_t stream) {
    const float* h   = (const float*)d_in[0];
    const float* adj = (const float*)d_in[1];
    const float* W   = (const float*)d_in[2];
    const float* a   = (const float*)d_in[3];
    float* out = (float*)d_out;

    unsigned short* Wb2 = (unsigned short*)d_ws;                          // 4 MB
    unsigned short* p16 = (unsigned short*)((char*)d_ws + (4u << 20));    // 32 KB

    k1_wh<<<NB * N / 64, 256, 0, stream>>>(h, W, a, Wb2, p16);
    k3_attn<<<NB * (N / 32), 256, 0, stream>>>(adj, Wb2, p16, out);
}